// Round 9
// baseline (303.816 us; speedup 1.0000x reference)
//
#include <hip/hip_runtime.h>

#define N_NODES 8000
#define FEAT 64
#define HID 128
#define LOOKBACK 12
#define CAP 64

// ---------------- zero the per-node counters ----------------
__global__ __launch_bounds__(256)
void zero_cnt_kernel(int* __restrict__ cnt) {
    int g = blockIdx.x * 256 + threadIdx.x;
    if (g < N_NODES) cnt[g] = 0;
}

// ---------------- adjacency pattern extraction (atomic) ----------------
__global__ __launch_bounds__(256)
void build_adj_kernel(const float* __restrict__ adj, int* __restrict__ cnt,
                      int* __restrict__ lists) {
    long q = (long)blockIdx.x * 256 + threadIdx.x;           // float4 index
    const long NQ = (long)N_NODES * N_NODES / 4;
    if (q >= NQ) return;
    int i  = (int)(q / (N_NODES / 4));
    int j0 = (int)(q % (N_NODES / 4)) * 4;
    float4 w = *reinterpret_cast<const float4*>(adj + (long)i * N_NODES + j0);
    float wv[4] = {w.x, w.y, w.z, w.w};
    #pragma unroll
    for (int c = 0; c < 4; ++c) {
        if (wv[c] != 0.0f) {
            int j = j0 + c;
            int p = atomicAdd(&cnt[j], 1);
            if (p < CAP) lists[(long)j * CAP + p] = i;       // edge i -> j
        }
    }
}

// ---------------- canonicalize: wave-bitonic sort per node + deg + weights ----
__global__ __launch_bounds__(256)
void prep_kernel(int* __restrict__ cnt, int* __restrict__ lists,
                 float* __restrict__ degf,
                 const float* __restrict__ Wl1, const float* __restrict__ Wr1,
                 const float* __restrict__ Wl2, const float* __restrict__ Wr2,
                 float* __restrict__ Ws1, float* __restrict__ Wc2) {
    if (blockIdx.x < 2000) {
        const int wv   = threadIdx.x >> 6;
        const int lane = threadIdx.x & 63;
        const int n = blockIdx.x * 4 + wv;
        int m = cnt[n];
        if (m > CAP) m = CAP;
        int v = (lane < m) ? lists[(long)n * CAP + lane] : 0x7FFFFFFF;
        #pragma unroll
        for (int k = 2; k <= 64; k <<= 1) {
            #pragma unroll
            for (int j = k >> 1; j > 0; j >>= 1) {
                int other = __shfl_xor(v, j);
                bool keepMin = (((lane & j) == 0) == ((lane & k) == 0));
                int mn = v < other ? v : other;
                int mx = v < other ? other : v;
                v = keepMin ? mn : mx;
            }
        }
        lists[(long)n * CAP + lane] = v;
        if (lane == 0) {
            cnt[n]  = m;
            degf[n] = (float)(m > 0 ? m : 1);
        }
    } else {
        int u = (blockIdx.x - 2000) * 256 + threadIdx.x;
        if (u < 128 * 128) {            // Ws1[k][j] = [Wl1;Wr1] row-stacked
            int k = u >> 7, j = u & 127;
            Ws1[u] = (k < 64) ? Wl1[k * 128 + j] : Wr1[(k - 64) * 128 + j];
        } else if (u < 2 * 128 * 128) { // Wc2[k][j] = [Wl2 | Wr2] col-stacked
            int w = u - 128 * 128;
            int k = w >> 7, j = w & 127;
            Wc2[w] = (j < 64) ? Wl2[k * 64 + j] : Wr2[k * 64 + (j - 64)];
        }
    }
}

// ---------------- init encoder: x[L,N,F] -> x0[N,F], 4 elems/thread ----------------
__global__ __launch_bounds__(256)
void init_enc_kernel(const float* __restrict__ x, const float* __restrict__ We1,
                     const float* __restrict__ be1, const float* __restrict__ We2,
                     const float* __restrict__ be2, float* __restrict__ out0) {
    __shared__ float sW1T[HID * LOOKBACK];   // [h][l]
    __shared__ float sB1[HID];
    __shared__ float sW2[HID];
    for (int e = threadIdx.x; e < HID * LOOKBACK; e += 256) {
        int l = e / HID, h = e % HID;
        sW1T[h * LOOKBACK + l] = We1[e];
    }
    for (int e = threadIdx.x; e < HID; e += 256) { sB1[e] = be1[e]; sW2[e] = We2[e]; }
    __syncthreads();
    int g = (blockIdx.x * 256 + threadIdx.x) * 4;
    if (g >= N_NODES * FEAT) return;
    float xv[4][LOOKBACK];
    #pragma unroll
    for (int l = 0; l < LOOKBACK; ++l) {
        float4 v = *reinterpret_cast<const float4*>(x + (long)l * N_NODES * FEAT + g);
        xv[0][l] = v.x; xv[1][l] = v.y; xv[2][l] = v.z; xv[3][l] = v.w;
    }
    float b2 = be2[0];
    float acc[4] = {b2, b2, b2, b2};
    for (int h = 0; h < HID; ++h) {
        float s0 = sB1[h], s1 = s0, s2 = s0, s3 = s0;
        #pragma unroll
        for (int l = 0; l < LOOKBACK; ++l) {
            float w = sW1T[h * LOOKBACK + l];
            s0 += xv[0][l] * w; s1 += xv[1][l] * w;
            s2 += xv[2][l] * w; s3 += xv[3][l] * w;
        }
        float w2 = sW2[h];
        acc[0] += fmaxf(s0, 0.0f) * w2; acc[1] += fmaxf(s1, 0.0f) * w2;
        acc[2] += fmaxf(s2, 0.0f) * w2; acc[3] += fmaxf(s3, 0.0f) * w2;
    }
    float4 o = {acc[0], acc[1], acc[2], acc[3]};
    *reinterpret_cast<float4*>(out0 + g) = o;
}

// ---------------- fused SAGE1 + proj + selfMLP, 4x4 register tile ----------------
// 32 nodes/block, 250 blocks. Activations in transposed LDS ([k][node], stride 36,
// b128 conflict-free); weights stream from global (L1/L2-hot, separate pipe).
// Thread (jg,lng): jg = tid>>3 owns cols 4jg..4jg+3; lng = tid&7 owns nodes 4lng..4lng+3.
__global__ __launch_bounds__(256)
void sageproj_kernel(const float* __restrict__ h, const int* __restrict__ lists,
                     const int* __restrict__ cnt, const float* __restrict__ degf,
                     const float* __restrict__ Ws1, const float* __restrict__ bl1,
                     const float* __restrict__ Wc2, const float* __restrict__ bl2,
                     const float* __restrict__ Wf1, const float* __restrict__ bf1,
                     const float* __restrict__ Wf2, const float* __restrict__ bf2,
                     float* __restrict__ pl, float* __restrict__ q) {
    // aliased LDS pool (63 KB): v (gather staging) dies before rrT is written
    __shared__ __align__(16) char pool[64512];
    float (*vT)[36]   = reinterpret_cast<float(*)[36]>(pool);            // [128][36]
    float (*rrT)[36]  = reinterpret_cast<float(*)[36]>(pool + 18432);    // [128][36]
    float (*ttT)[36]  = reinterpret_cast<float(*)[36]>(pool + 36864);    // [128][36]
    float (*xslT)[36] = reinterpret_cast<float(*)[36]>(pool + 55296);    // [64][36]
    float (*v)[132]   = reinterpret_cast<float(*)[132]>(pool + 18432);   // [32][132] aliases rrT

    const int tid = threadIdx.x;
    const int nb = blockIdx.x * 32;
    {   // gather: 8 threads/node, 8 feats each -> v[node][k] (k<64 aggr, k>=64 h)
        const int ln = tid >> 3, sub = tid & 7;
        const int n = nb + ln;
        const int f0 = sub * 8;
        const int m = cnt[n];
        const int* l = lists + (long)n * CAP;
        const float inv = 1.0f / degf[n];
        float acc[8] = {0, 0, 0, 0, 0, 0, 0, 0};
        for (int e = 0; e < m; ++e) {
            const float* hp = h + (long)l[e] * FEAT + f0;
            float4 b0 = *reinterpret_cast<const float4*>(hp);
            float4 b1 = *reinterpret_cast<const float4*>(hp + 4);
            acc[0] += b0.x; acc[1] += b0.y; acc[2] += b0.z; acc[3] += b0.w;
            acc[4] += b1.x; acc[5] += b1.y; acc[6] += b1.z; acc[7] += b1.w;
        }
        float4 a0 = {acc[0] * inv, acc[1] * inv, acc[2] * inv, acc[3] * inv};
        float4 a1 = {acc[4] * inv, acc[5] * inv, acc[6] * inv, acc[7] * inv};
        *reinterpret_cast<float4*>(&v[ln][f0])     = a0;
        *reinterpret_cast<float4*>(&v[ln][f0 + 4]) = a1;
        const float* hn = h + (long)n * FEAT + f0;
        *reinterpret_cast<float4*>(&v[ln][64 + f0])     = *reinterpret_cast<const float4*>(hn);
        *reinterpret_cast<float4*>(&v[ln][64 + f0 + 4]) = *reinterpret_cast<const float4*>(hn + 4);
    }
    __syncthreads();
    // transpose v[node][k] -> vT[k][node]
    {
        const int k = tid & 127;
        const int no = (tid >> 7) * 16;          // node-octet base: 0 or 16
        float t0[16];
        #pragma unroll
        for (int j = 0; j < 16; ++j) t0[j] = v[no + j][k];
        #pragma unroll
        for (int i = 0; i < 4; ++i) {
            float4 o = {t0[4*i], t0[4*i+1], t0[4*i+2], t0[4*i+3]};
            *reinterpret_cast<float4*>(&vT[k][no + 4*i]) = o;
        }
    }
    __syncthreads();
    const int jg = tid >> 3, lng = tid & 7;
    const int c0 = jg * 4, n0 = lng * 4;
    // P1: rrT = relu(vT^T @ Ws1 + bl1), K=128
    {
        float acc[4][4];
        #pragma unroll
        for (int c = 0; c < 4; ++c) {
            float b = bl1[c0 + c];
            #pragma unroll
            for (int n = 0; n < 4; ++n) acc[c][n] = b;
        }
        #pragma unroll 4
        for (int k = 0; k < 128; ++k) {
            float4 a = *reinterpret_cast<const float4*>(&vT[k][n0]);
            float4 w = *reinterpret_cast<const float4*>(Ws1 + k * 128 + c0);
            float av[4] = {a.x, a.y, a.z, a.w};
            float wv[4] = {w.x, w.y, w.z, w.w};
            #pragma unroll
            for (int c = 0; c < 4; ++c)
                #pragma unroll
                for (int n = 0; n < 4; ++n)
                    acc[c][n] += av[n] * wv[c];
        }
        #pragma unroll
        for (int c = 0; c < 4; ++c) {
            float4 o = {fmaxf(acc[c][0],0.f), fmaxf(acc[c][1],0.f),
                        fmaxf(acc[c][2],0.f), fmaxf(acc[c][3],0.f)};
            *reinterpret_cast<float4*>(&rrT[c0 + c][n0]) = o;
        }
    }
    // P2: ttT = relu(h @ Wf1 + bf1), K=64 (h part of vT)
    {
        float acc[4][4];
        #pragma unroll
        for (int c = 0; c < 4; ++c) {
            float b = bf1[c0 + c];
            #pragma unroll
            for (int n = 0; n < 4; ++n) acc[c][n] = b;
        }
        #pragma unroll 4
        for (int k = 0; k < 64; ++k) {
            float4 a = *reinterpret_cast<const float4*>(&vT[64 + k][n0]);
            float4 w = *reinterpret_cast<const float4*>(Wf1 + k * 128 + c0);
            float av[4] = {a.x, a.y, a.z, a.w};
            float wv[4] = {w.x, w.y, w.z, w.w};
            #pragma unroll
            for (int c = 0; c < 4; ++c)
                #pragma unroll
                for (int n = 0; n < 4; ++n)
                    acc[c][n] += av[n] * wv[c];
        }
        #pragma unroll
        for (int c = 0; c < 4; ++c) {
            float4 o = {fmaxf(acc[c][0],0.f), fmaxf(acc[c][1],0.f),
                        fmaxf(acc[c][2],0.f), fmaxf(acc[c][3],0.f)};
            *reinterpret_cast<float4*>(&ttT[c0 + c][n0]) = o;
        }
    }
    __syncthreads();     // ttT ready (and rrT, vT no longer needed for writes)
    // P3: xslT = ttT^T @ Wf2 + bf2, 64 cols (jg < 16 active), K=128
    if (jg < 16) {
        float acc[4][4];
        #pragma unroll
        for (int c = 0; c < 4; ++c) {
            float b = bf2[c0 + c];
            #pragma unroll
            for (int n = 0; n < 4; ++n) acc[c][n] = b;
        }
        #pragma unroll 4
        for (int k = 0; k < 128; ++k) {
            float4 a = *reinterpret_cast<const float4*>(&ttT[k][n0]);
            float4 w = *reinterpret_cast<const float4*>(Wf2 + k * 64 + c0);
            float av[4] = {a.x, a.y, a.z, a.w};
            float wv[4] = {w.x, w.y, w.z, w.w};
            #pragma unroll
            for (int c = 0; c < 4; ++c)
                #pragma unroll
                for (int n = 0; n < 4; ++n)
                    acc[c][n] += av[n] * wv[c];
        }
        #pragma unroll
        for (int c = 0; c < 4; ++c) {
            float4 o = {acc[c][0], acc[c][1], acc[c][2], acc[c][3]};
            *reinterpret_cast<float4*>(&xslT[c0 + c][n0]) = o;
        }
    }
    __syncthreads();     // xslT ready
    // P4: P = rrT^T @ Wc2; cols<64 -> pl, cols>=64 -> q (+ bl2 + xsl), K=128
    {
        float acc[4][4];
        #pragma unroll
        for (int c = 0; c < 4; ++c)
            #pragma unroll
            for (int n = 0; n < 4; ++n) acc[c][n] = 0.0f;
        #pragma unroll 4
        for (int k = 0; k < 128; ++k) {
            float4 a = *reinterpret_cast<const float4*>(&rrT[k][n0]);
            float4 w = *reinterpret_cast<const float4*>(Wc2 + k * 128 + c0);
            float av[4] = {a.x, a.y, a.z, a.w};
            float wv[4] = {w.x, w.y, w.z, w.w};
            #pragma unroll
            for (int c = 0; c < 4; ++c)
                #pragma unroll
                for (int n = 0; n < 4; ++n)
                    acc[c][n] += av[n] * wv[c];
        }
        if (jg < 16) {                               // pl cols c0..c0+3
            #pragma unroll
            for (int n = 0; n < 4; ++n) {
                float4 o = {acc[0][n], acc[1][n], acc[2][n], acc[3][n]};
                *reinterpret_cast<float4*>(pl + (long)(nb + n0 + n) * FEAT + c0) = o;
            }
        } else {                                     // q cols cq..cq+3
            const int cq = c0 - 64;
            #pragma unroll
            for (int n = 0; n < 4; ++n) {
                float4 o = {acc[0][n] + bl2[cq + 0] + xslT[cq + 0][n0 + n],
                            acc[1][n] + bl2[cq + 1] + xslT[cq + 1][n0 + n],
                            acc[2][n] + bl2[cq + 2] + xslT[cq + 2][n0 + n],
                            acc[3][n] + bl2[cq + 3] + xslT[cq + 3][n0 + n]};
                *reinterpret_cast<float4*>(q + (long)(nb + n0 + n) * FEAT + cq) = o;
            }
        }
    }
}

// ---------------- gather + Euler epilogue ----------------
__global__ __launch_bounds__(256)
void epi_kernel(const float* __restrict__ pl, const float* __restrict__ q,
                const int* __restrict__ lists, const int* __restrict__ cnt,
                const float* __restrict__ degf, const float* __restrict__ hcur,
                const float* __restrict__ tspan, int step,
                float* __restrict__ hnext) {
    const int tid = threadIdx.x;
    const int ln = tid >> 4, sub = tid & 15;
    const int n = blockIdx.x * 16 + ln;
    const int f0 = sub * 4;
    const int m = cnt[n];
    const int* l = lists + (long)n * CAP;
    const float inv = 1.0f / degf[n];
    float4 a = {0, 0, 0, 0};
    for (int e = 0; e < m; ++e) {
        float4 b = *reinterpret_cast<const float4*>(pl + (long)l[e] * FEAT + f0);
        a.x += b.x; a.y += b.y; a.z += b.z; a.w += b.w;
    }
    const float dt = tspan[step + 1] - tspan[step];
    float4 qv = *reinterpret_cast<const float4*>(q + (long)n * FEAT + f0);
    float4 hv = *reinterpret_cast<const float4*>(hcur + (long)n * FEAT + f0);
    float s0 = qv.x + a.x * inv, s1 = qv.y + a.y * inv;
    float s2 = qv.z + a.z * inv, s3 = qv.w + a.w * inv;
    s0 = fminf(fmaxf(s0, -1000.f), 1000.f); s1 = fminf(fmaxf(s1, -1000.f), 1000.f);
    s2 = fminf(fmaxf(s2, -1000.f), 1000.f); s3 = fminf(fmaxf(s3, -1000.f), 1000.f);
    float4 o = {hv.x + dt * s0, hv.y + dt * s1, hv.z + dt * s2, hv.w + dt * s3};
    *reinterpret_cast<float4*>(hnext + (long)n * FEAT + f0) = o;
}

extern "C" void kernel_launch(void* const* d_in, const int* in_sizes, int n_in,
                              void* d_out, int out_size, void* d_ws, size_t ws_size,
                              hipStream_t stream) {
    const float* tspan = (const float*)d_in[0];
    const float* x     = (const float*)d_in[1];
    const float* adj   = (const float*)d_in[2];
    const float* We1   = (const float*)d_in[3];
    const float* be1   = (const float*)d_in[4];
    const float* We2   = (const float*)d_in[5];
    const float* be2   = (const float*)d_in[6];
    const float* Wf1   = (const float*)d_in[7];
    const float* bf1   = (const float*)d_in[8];
    const float* Wf2   = (const float*)d_in[9];
    const float* bf2   = (const float*)d_in[10];
    const float* Wl1   = (const float*)d_in[11];
    const float* bl1   = (const float*)d_in[12];
    const float* Wr1   = (const float*)d_in[13];
    const float* Wl2   = (const float*)d_in[14];
    const float* bl2   = (const float*)d_in[15];
    const float* Wr2   = (const float*)d_in[16];
    float* out = (float*)d_out;

    // workspace layout (bytes)
    char* ws = (char*)d_ws;
    int*   lists = (int*)  (ws + 0);           // 8000*64*4  = 2,048,000
    int*   cnt   = (int*)  (ws + 2048000);     // 32,000
    float* degf  = (float*)(ws + 2080000);     // 32,000
    float* Ws1   = (float*)(ws + 2112000);     // 65,536
    float* Wc2   = (float*)(ws + 2177536);     // 65,536
    float* pl    = (float*)(ws + 2243072);     // 2,048,000
    float* q     = (float*)(ws + 4291072);     // 2,048,000
    // total 6,339,072 bytes

    zero_cnt_kernel<<<32, 256, 0, stream>>>(cnt);
    build_adj_kernel<<<62500, 256, 0, stream>>>(adj, cnt, lists);
    prep_kernel<<<2128, 256, 0, stream>>>(cnt, lists, degf, Wl1, Wr1, Wl2, Wr2, Ws1, Wc2);
    init_enc_kernel<<<500, 256, 0, stream>>>(x, We1, be1, We2, be2, out);

    for (int s = 0; s < 3; ++s) {
        const float* hcur  = out + (long)s       * N_NODES * FEAT;
        float*       hnext = out + (long)(s + 1) * N_NODES * FEAT;
        sageproj_kernel<<<250, 256, 0, stream>>>(hcur, lists, cnt, degf,
                                                 Ws1, bl1, Wc2, bl2,
                                                 Wf1, bf1, Wf2, bf2, pl, q);
        epi_kernel<<<500, 256, 0, stream>>>(pl, q, lists, cnt, degf, hcur, tspan, s, hnext);
    }
}